// Round 1
// baseline (162.389 us; speedup 1.0000x reference)
//
#include <hip/hip_runtime.h>
#include <math.h>

#define BATCH 64
#define DIM 512
#define NPATCH 128
#define SSZ 64
#define PADZ 516  // 512 floats + 4 pad: breaks LDS bank alignment (2-way max, free)

typedef float f32x4 __attribute__((ext_vector_type(4)));

// ---------------------------------------------------------------------------
// Kernel A: the whole 64x1920 GEMM + epilogue, output as 16-float records
// ws[(b*128+p)*16 + r]: r=0..8 -> (1-sigmoid(.))*noise masks, r=9..14 -> theta.
//
// Grid (128 patches, 4 batch-quarters) x 256 threads. Each block:
//   - stages its 16 z-rows (32 KB) into padded LDS,
//   - thread t = r*16 + bl computes the FULL 512-dot for (row r, batch bl):
//     the 16 lanes of a row-group read the SAME W float4 (hardware broadcast,
//     one transaction) and 16 different padded z rows from LDS (2-way bank
//     alias only). No cross-lane reduction at all.
// W is read 4x total (once per batch-quarter) = 15.6 MB -> trivial.
// ---------------------------------------------------------------------------
__global__ __launch_bounds__(256) void k_gemm(
    const float* __restrict__ z, const float* __restrict__ Wm,
    const float* __restrict__ bm, const float* __restrict__ Wt,
    const float* __restrict__ bt, const float* __restrict__ noise,
    float* __restrict__ ws) {
  __shared__ float zs[16 * PADZ];
  const int p = blockIdx.x;   // 0..127
  const int bq = blockIdx.y;  // 0..3
  const int t = threadIdx.x;

  // stage 16 z rows: 2048 float4 / 256 threads = 8 each
  {
    const f32x4* __restrict__ src = (const f32x4*)(z + (size_t)(bq * 16) * DIM);
#pragma unroll
    for (int i = 0; i < 8; ++i) {
      const int idx = t + (i << 8);   // float4 index 0..2047
      const int row = idx >> 7;       // 128 float4 per row
      const int col = idx & 127;
      *(f32x4*)(zs + row * PADZ + (col << 2)) = src[idx];
    }
  }
  __syncthreads();

  const int r = t >> 4;    // output row 0..15 (15 idle)
  const int bl = t & 15;   // batch within quarter
  if (r >= 15) return;     // no barriers after this point

  const float* __restrict__ wrow =
      (r < 9) ? (Wm + (size_t)(p * 9 + r) * DIM)
              : (Wt + (size_t)(p * 6 + (r - 9)) * DIM);
  const float* __restrict__ zr = zs + bl * PADZ;

  float a0 = 0.0f, a1 = 0.0f, a2 = 0.0f, a3 = 0.0f;
#pragma unroll 8
  for (int i = 0; i < 128; ++i) {
    const f32x4 wv = ((const f32x4*)wrow)[i];
    const f32x4 zv = *(const f32x4*)(zr + (i << 2));
    a0 = fmaf(wv.x, zv.x, a0);
    a1 = fmaf(wv.y, zv.y, a1);
    a2 = fmaf(wv.z, zv.z, a2);
    a3 = fmaf(wv.w, zv.w, a3);
  }
  const float acc = (a0 + a1) + (a2 + a3);

  const int b = (bq << 4) + bl;
  float v;
  if (r < 9) {
    // 1 - sigmoid(x) = 1/(1+exp(x)), then patch noise
    v = (1.0f / (1.0f + expf(acc + bm[p * 9 + r]))) * noise[r];
  } else {
    v = acc + bt[p * 6 + (r - 9)];
  }
  ws[(((size_t)b << 7) + p) * 16 + r] = v;
}

// ---------------------------------------------------------------------------
// Kernel B: sampler only. One block per (b,p) image, 256 threads, 16 px each.
// Reads its 15-float record via LDS broadcast; bilinear-with-zeros over the
// 3x3 mask in the tensor-product hat basis. hat(t)=max(0,1-|t|) with arms
// summing to 2 is exactly v_med3(0, 1+t, 1-t); arms maintained incrementally
// along w (ax += dix, bx -= dix). 26 VALU/pixel.
// Stores: each thread 4x float4, wave = 1 KiB contiguous; nontemporal
// (write-once stream, skip L2 write-allocate).
// VGPR ~40 -> 8 waves/SIMD; no W/z traffic competing with the store stream.
// ---------------------------------------------------------------------------
__global__ __launch_bounds__(256) void k_sample(
    const float* __restrict__ ws, float* __restrict__ out) {
  __shared__ float sm[16];
  const int t = threadIdx.x;
  const int bp = blockIdx.x;  // b*128 + p
  if (t < 16) sm[t] = ws[((size_t)bp << 4) + t];
  __syncthreads();

  const float m00 = sm[0], m01 = sm[1], m02 = sm[2];
  const float m10 = sm[3], m11 = sm[4], m12 = sm[5];
  const float m20 = sm[6], m21 = sm[7], m22 = sm[8];
  const float th0 = sm[9], th1 = sm[10], th2 = sm[11];
  const float th3 = sm[12], th4 = sm[13], th5 = sm[14];

  const int w4 = (t & 15) << 2;  // 4 consecutive w
  const int hb = t >> 4;         // base row 0..15
  const float cx0 = (w4 + 0.5f) * (1.0f / 32.0f) - 1.0f;
  const float cy0 = (hb + 0.5f) * (1.0f / 32.0f) - 1.0f;
  const float dix = th0 * (1.5f / 32.0f);  // per-w step of ix
  const float diy = th3 * (1.5f / 32.0f);
  const float Bx = 1.5f * th1, By = 1.5f * th4;
  const float Px = fmaf(1.5f, fmaf(th0, cx0, th2), 1.0f);
  const float Py = fmaf(1.5f, fmaf(th3, cx0, th5), 1.0f);

  float* op = out + ((size_t)bp << 12) + hb * 64 + w4;

#pragma unroll
  for (int i = 0; i < 4; ++i) {
    const float cy = cy0 + 0.5f * i;  // row hb + 16*i
    const float ix = fmaf(Bx, cy, Px);
    const float iy = fmaf(By, cy, Py);
    float ax = ix + 1.0f, bx = 1.0f - ix;  // hat arms, sum == 2
    float ay = iy + 1.0f, by = 1.0f - iy;
    f32x4 rv;
#pragma unroll
    for (int j = 0; j < 4; ++j) {
      const float wx0 = __builtin_amdgcn_fmed3f(0.0f, ax, bx);
      const float wx1 = __builtin_amdgcn_fmed3f(0.0f, ax - 1.0f, bx + 1.0f);
      const float wx2 = __builtin_amdgcn_fmed3f(0.0f, ax - 2.0f, bx + 2.0f);
      const float wy0 = __builtin_amdgcn_fmed3f(0.0f, ay, by);
      const float wy1 = __builtin_amdgcn_fmed3f(0.0f, ay - 1.0f, by + 1.0f);
      const float wy2 = __builtin_amdgcn_fmed3f(0.0f, ay - 2.0f, by + 2.0f);
      const float s0 = fmaf(m02, wx2, fmaf(m01, wx1, m00 * wx0));
      const float s1 = fmaf(m12, wx2, fmaf(m11, wx1, m10 * wx0));
      const float s2 = fmaf(m22, wx2, fmaf(m21, wx1, m20 * wx0));
      rv[j] = fmaf(wy2, s2, fmaf(wy1, s1, wy0 * s0));
      ax += dix; bx -= dix;
      ay += diy; by -= diy;
    }
    __builtin_nontemporal_store(rv, (f32x4*)(op + i * 16 * 64));
  }
}

// ---------------------------------------------------------------------------
// Fallback: previous fused kernel (verified, ~80 us) if ws is unavailable.
// ---------------------------------------------------------------------------
__global__ __launch_bounds__(256) void k_fused(
    const float* __restrict__ z, const float* __restrict__ Wm,
    const float* __restrict__ bm, const float* __restrict__ Wt,
    const float* __restrict__ bt, const float* __restrict__ noise,
    float* __restrict__ out) {
  __shared__ float sm[16];

  const int t = threadIdx.x;
  const int bp = blockIdx.x;
  const int b = bp >> 7;
  const int p = bp & 127;

  const int r = t >> 4;
  const int c = t & 15;
  float acc = 0.0f;
  if (r < 15) {
    const float* __restrict__ wrow =
        (r < 9) ? (Wm + (size_t)(p * 9 + r) * DIM)
                : (Wt + (size_t)(p * 6 + (r - 9)) * DIM);
    const float* __restrict__ zrow = z + (size_t)b * DIM;
#pragma unroll
    for (int i = 0; i < 8; ++i) {
      const float4 wv = *(const float4*)(wrow + i * 64 + c * 4);
      const float4 zv = *(const float4*)(zrow + i * 64 + c * 4);
      acc = fmaf(wv.x, zv.x, acc);
      acc = fmaf(wv.y, zv.y, acc);
      acc = fmaf(wv.z, zv.z, acc);
      acc = fmaf(wv.w, zv.w, acc);
    }
  }
  acc += __shfl_xor(acc, 1);
  acc += __shfl_xor(acc, 2);
  acc += __shfl_xor(acc, 4);
  acc += __shfl_xor(acc, 8);
  if (c == 0 && r < 15) {
    float v = acc;
    if (r < 9) {
      v = (1.0f / (1.0f + expf(v + bm[p * 9 + r]))) * noise[r];
    } else {
      v += bt[p * 6 + (r - 9)];
    }
    sm[r] = v;
  }
  __syncthreads();

  const float m00 = sm[0], m01 = sm[1], m02 = sm[2];
  const float m10 = sm[3], m11 = sm[4], m12 = sm[5];
  const float m20 = sm[6], m21 = sm[7], m22 = sm[8];
  const float th0 = sm[9], th1 = sm[10], th2 = sm[11];
  const float th3 = sm[12], th4 = sm[13], th5 = sm[14];

  const int w4 = (t & 15) << 2;
  const int hb = t >> 4;
  const float cx0 = (w4 + 0.5f) * (1.0f / 32.0f) - 1.0f;
  const float cy0 = (hb + 0.5f) * (1.0f / 32.0f) - 1.0f;
  const float dix = th0 * (1.5f / 32.0f);
  const float diy = th3 * (1.5f / 32.0f);
  const float Bx = 1.5f * th1, By = 1.5f * th4;
  const float Px = fmaf(1.5f, fmaf(th0, cx0, th2), 1.0f);
  const float Py = fmaf(1.5f, fmaf(th3, cx0, th5), 1.0f);

  float* op = out + ((size_t)bp << 12) + hb * 64 + w4;

#pragma unroll
  for (int i = 0; i < 4; ++i) {
    const float cy = cy0 + 0.5f * i;
    float ix = fmaf(Bx, cy, Px);
    float iy = fmaf(By, cy, Py);
    float4 rv;
    float* rp = &rv.x;
#pragma unroll
    for (int j = 0; j < 4; ++j) {
      const float wx0 = fmaxf(1.0f - fabsf(ix), 0.0f);
      const float wx1 = fmaxf(1.0f - fabsf(ix - 1.0f), 0.0f);
      const float wx2 = fmaxf(1.0f - fabsf(ix - 2.0f), 0.0f);
      const float wy0 = fmaxf(1.0f - fabsf(iy), 0.0f);
      const float wy1 = fmaxf(1.0f - fabsf(iy - 1.0f), 0.0f);
      const float wy2 = fmaxf(1.0f - fabsf(iy - 2.0f), 0.0f);
      const float s0 = fmaf(m02, wx2, fmaf(m01, wx1, m00 * wx0));
      const float s1 = fmaf(m12, wx2, fmaf(m11, wx1, m10 * wx0));
      const float s2 = fmaf(m22, wx2, fmaf(m21, wx1, m20 * wx0));
      rp[j] = fmaf(wy2, s2, fmaf(wy1, s1, wy0 * s0));
      ix += dix;
      iy += diy;
    }
    *(float4*)(op + i * 16 * 64) = rv;
  }
}

extern "C" void kernel_launch(void* const* d_in, const int* in_sizes, int n_in,
                              void* d_out, int out_size, void* d_ws, size_t ws_size,
                              hipStream_t stream) {
  const float* z     = (const float*)d_in[0];
  const float* Wm    = (const float*)d_in[1];
  const float* bm    = (const float*)d_in[2];
  const float* Wt    = (const float*)d_in[3];
  const float* bt    = (const float*)d_in[4];
  const float* noise = (const float*)d_in[5];
  float* out = (float*)d_out;

  const size_t need = (size_t)BATCH * NPATCH * 16 * sizeof(float);
  if (d_ws != nullptr && ws_size >= need) {
    float* ws = (float*)d_ws;
    hipLaunchKernelGGL(k_gemm, dim3(NPATCH, 4), dim3(256), 0, stream,
                       z, Wm, bm, Wt, bt, noise, ws);
    hipLaunchKernelGGL(k_sample, dim3(BATCH * NPATCH), dim3(256), 0, stream,
                       ws, out);
  } else {
    hipLaunchKernelGGL(k_fused, dim3(BATCH * NPATCH), dim3(256), 0, stream,
                       z, Wm, bm, Wt, bt, noise, out);
  }
}

// Round 3
// 159.688 us; speedup vs baseline: 1.0169x; 1.0169x over previous
//
#include <hip/hip_runtime.h>
#include <math.h>

#define BATCH 64
#define DIM 512
#define NPATCH 128
#define SSZ 64
#define PADZ 516  // 512 floats + 4 pad: breaks LDS bank alignment (2-way max, free)

typedef float f32x4 __attribute__((ext_vector_type(4)));

// ---------------------------------------------------------------------------
// Kernel A (unchanged, verified r1): whole 64x1920 GEMM + epilogue ->
// 16-float records ws[(b*128+p)*16 + r]: r=0..8 masks (1-sigmoid)*noise,
// r=9..14 theta. Grid (128 patches, 4 batch-quarters) x 256 threads;
// z staged in padded LDS; W rows hardware-broadcast across 16-lane groups.
// ---------------------------------------------------------------------------
__global__ __launch_bounds__(256) void k_gemm(
    const float* __restrict__ z, const float* __restrict__ Wm,
    const float* __restrict__ bm, const float* __restrict__ Wt,
    const float* __restrict__ bt, const float* __restrict__ noise,
    float* __restrict__ ws) {
  __shared__ float zs[16 * PADZ];
  const int p = blockIdx.x;   // 0..127
  const int bq = blockIdx.y;  // 0..3
  const int t = threadIdx.x;

  {
    const f32x4* __restrict__ src = (const f32x4*)(z + (size_t)(bq * 16) * DIM);
#pragma unroll
    for (int i = 0; i < 8; ++i) {
      const int idx = t + (i << 8);
      const int row = idx >> 7;
      const int col = idx & 127;
      *(f32x4*)(zs + row * PADZ + (col << 2)) = src[idx];
    }
  }
  __syncthreads();

  const int r = t >> 4;    // output row 0..15 (15 idle)
  const int bl = t & 15;   // batch within quarter
  if (r >= 15) return;     // no barriers after this point

  const float* __restrict__ wrow =
      (r < 9) ? (Wm + (size_t)(p * 9 + r) * DIM)
              : (Wt + (size_t)(p * 6 + (r - 9)) * DIM);
  const float* __restrict__ zr = zs + bl * PADZ;

  float a0 = 0.0f, a1 = 0.0f, a2 = 0.0f, a3 = 0.0f;
#pragma unroll 8
  for (int i = 0; i < 128; ++i) {
    const f32x4 wv = ((const f32x4*)wrow)[i];
    const f32x4 zv = *(const f32x4*)(zr + (i << 2));
    a0 = fmaf(wv.x, zv.x, a0);
    a1 = fmaf(wv.y, zv.y, a1);
    a2 = fmaf(wv.z, zv.z, a2);
    a3 = fmaf(wv.w, zv.w, a3);
  }
  const float acc = (a0 + a1) + (a2 + a3);

  const int b = (bq << 4) + bl;
  float v;
  if (r < 9) {
    v = (1.0f / (1.0f + expf(acc + bm[p * 9 + r]))) * noise[r];
  } else {
    v = acc + bt[p * 6 + (r - 9)];
  }
  ws[(((size_t)b << 7) + p) * 16 + r] = v;
}

// ---------------------------------------------------------------------------
// Kernel B v3: streaming sampler. ONE WAVE OWNS ONE IMAGE (16 KiB) and walks
// it LINEARLY: 16 units x one contiguous 1-KiB wave store at strictly
// increasing addresses — the same access shape as the 6.3 TB/s harness fill.
// Plain stores (through L2). r2 bug fixed: a 4-row unit is 256 FLOATS, so
// op += 256 (r2's op += 1024 strode 4x past the image -> memory fault).
//
// Lane l: w-quad (l&15)*4, sub-row l>>4. Unit a covers rows 4a..4a+3.
// Record (15 floats) broadcast via one load + __shfl — no LDS, no barriers.
// Per-unit base ix/iy computed by fmaf(a, step, base) (no drift);
// per-w step incremental inside the quad. hat(t)=max(0,1-|t|)
// = v_med3(0, 1+t, 1-t).
// ---------------------------------------------------------------------------
__global__ __launch_bounds__(256) void k_sample(
    const float* __restrict__ ws, float* __restrict__ out) {
  const int lane = threadIdx.x & 63;
  const int bp = (blockIdx.x << 2) | (threadIdx.x >> 6);  // wave id = image

  // broadcast the 16-float record across the wave
  const float rec = ws[((size_t)bp << 4) + (lane & 15)];
  const float m00 = __shfl(rec, 0), m01 = __shfl(rec, 1), m02 = __shfl(rec, 2);
  const float m10 = __shfl(rec, 3), m11 = __shfl(rec, 4), m12 = __shfl(rec, 5);
  const float m20 = __shfl(rec, 6), m21 = __shfl(rec, 7), m22 = __shfl(rec, 8);
  const float th0 = __shfl(rec, 9), th1 = __shfl(rec, 10), th2 = __shfl(rec, 11);
  const float th3 = __shfl(rec, 12), th4 = __shfl(rec, 13), th5 = __shfl(rec, 14);

  const int w4 = (lane & 15) << 2;  // 4 consecutive w per lane
  const int rsub = lane >> 4;       // sub-row 0..3 within unit
  const float cx0 = (w4 + 0.5f) * (1.0f / 32.0f) - 1.0f;
  const float cy0 = (rsub + 0.5f) * (1.0f / 32.0f) - 1.0f;
  const float dix = th0 * (1.5f / 32.0f);   // per-w step
  const float diy = th3 * (1.5f / 32.0f);
  const float dAx = th1 * (1.5f * 0.125f);  // per-unit (4-row) step
  const float dAy = th4 * (1.5f * 0.125f);
  // ix = 1.5*(th0*cx + th1*cy + th2) + 1 at (a=0, j=0)
  const float ixb0 = fmaf(1.5f, fmaf(th0, cx0, fmaf(th1, cy0, th2)), 1.0f);
  const float iyb0 = fmaf(1.5f, fmaf(th3, cx0, fmaf(th4, cy0, th5)), 1.0f);

  float* op = out + ((size_t)bp << 12) + (rsub << 6) + w4;

#pragma unroll 2
  for (int a = 0; a < 16; ++a) {
    float ix = fmaf((float)a, dAx, ixb0);
    float iy = fmaf((float)a, dAy, iyb0);
    f32x4 rv;
#pragma unroll
    for (int j = 0; j < 4; ++j) {
      const float ax = ix + 1.0f, bx = 1.0f - ix;  // hat arms, sum == 2
      const float ay = iy + 1.0f, by = 1.0f - iy;
      const float wx0 = __builtin_amdgcn_fmed3f(0.0f, ax, bx);
      const float wx1 = __builtin_amdgcn_fmed3f(0.0f, ax - 1.0f, bx + 1.0f);
      const float wx2 = __builtin_amdgcn_fmed3f(0.0f, ax - 2.0f, bx + 2.0f);
      const float wy0 = __builtin_amdgcn_fmed3f(0.0f, ay, by);
      const float wy1 = __builtin_amdgcn_fmed3f(0.0f, ay - 1.0f, by + 1.0f);
      const float wy2 = __builtin_amdgcn_fmed3f(0.0f, ay - 2.0f, by + 2.0f);
      const float s0 = fmaf(m02, wx2, fmaf(m01, wx1, m00 * wx0));
      const float s1 = fmaf(m12, wx2, fmaf(m11, wx1, m10 * wx0));
      const float s2 = fmaf(m22, wx2, fmaf(m21, wx1, m20 * wx0));
      rv[j] = fmaf(wy2, s2, fmaf(wy1, s1, wy0 * s0));
      ix += dix;
      iy += diy;
    }
    *(f32x4*)op = rv;   // contiguous 1 KiB per wave, sequential in a
    op += 256;          // next 4-row unit = 256 floats = 1 KiB
  }
}

// ---------------------------------------------------------------------------
// Fallback: fused single-kernel path (verified) if ws is unavailable.
// ---------------------------------------------------------------------------
__global__ __launch_bounds__(256) void k_fused(
    const float* __restrict__ z, const float* __restrict__ Wm,
    const float* __restrict__ bm, const float* __restrict__ Wt,
    const float* __restrict__ bt, const float* __restrict__ noise,
    float* __restrict__ out) {
  __shared__ float sm[16];

  const int t = threadIdx.x;
  const int bp = blockIdx.x;
  const int b = bp >> 7;
  const int p = bp & 127;

  const int r = t >> 4;
  const int c = t & 15;
  float acc = 0.0f;
  if (r < 15) {
    const float* __restrict__ wrow =
        (r < 9) ? (Wm + (size_t)(p * 9 + r) * DIM)
                : (Wt + (size_t)(p * 6 + (r - 9)) * DIM);
    const float* __restrict__ zrow = z + (size_t)b * DIM;
#pragma unroll
    for (int i = 0; i < 8; ++i) {
      const float4 wv = *(const float4*)(wrow + i * 64 + c * 4);
      const float4 zv = *(const float4*)(zrow + i * 64 + c * 4);
      acc = fmaf(wv.x, zv.x, acc);
      acc = fmaf(wv.y, zv.y, acc);
      acc = fmaf(wv.z, zv.z, acc);
      acc = fmaf(wv.w, zv.w, acc);
    }
  }
  acc += __shfl_xor(acc, 1);
  acc += __shfl_xor(acc, 2);
  acc += __shfl_xor(acc, 4);
  acc += __shfl_xor(acc, 8);
  if (c == 0 && r < 15) {
    float v = acc;
    if (r < 9) {
      v = (1.0f / (1.0f + expf(v + bm[p * 9 + r]))) * noise[r];
    } else {
      v += bt[p * 6 + (r - 9)];
    }
    sm[r] = v;
  }
  __syncthreads();

  const float m00 = sm[0], m01 = sm[1], m02 = sm[2];
  const float m10 = sm[3], m11 = sm[4], m12 = sm[5];
  const float m20 = sm[6], m21 = sm[7], m22 = sm[8];
  const float th0 = sm[9], th1 = sm[10], th2 = sm[11];
  const float th3 = sm[12], th4 = sm[13], th5 = sm[14];

  const int w4 = (t & 15) << 2;
  const int hb = t >> 4;
  const float cx0 = (w4 + 0.5f) * (1.0f / 32.0f) - 1.0f;
  const float cy0 = (hb + 0.5f) * (1.0f / 32.0f) - 1.0f;
  const float dix = th0 * (1.5f / 32.0f);
  const float diy = th3 * (1.5f / 32.0f);
  const float Bx = 1.5f * th1, By = 1.5f * th4;
  const float Px = fmaf(1.5f, fmaf(th0, cx0, th2), 1.0f);
  const float Py = fmaf(1.5f, fmaf(th3, cx0, th5), 1.0f);

  float* op = out + ((size_t)bp << 12) + hb * 64 + w4;

#pragma unroll
  for (int i = 0; i < 4; ++i) {
    const float cy = cy0 + 0.5f * i;
    float ix = fmaf(Bx, cy, Px);
    float iy = fmaf(By, cy, Py);
    float4 rv;
    float* rp = &rv.x;
#pragma unroll
    for (int j = 0; j < 4; ++j) {
      const float wx0 = fmaxf(1.0f - fabsf(ix), 0.0f);
      const float wx1 = fmaxf(1.0f - fabsf(ix - 1.0f), 0.0f);
      const float wx2 = fmaxf(1.0f - fabsf(ix - 2.0f), 0.0f);
      const float wy0 = fmaxf(1.0f - fabsf(iy), 0.0f);
      const float wy1 = fmaxf(1.0f - fabsf(iy - 1.0f), 0.0f);
      const float wy2 = fmaxf(1.0f - fabsf(iy - 2.0f), 0.0f);
      const float s0 = fmaf(m02, wx2, fmaf(m01, wx1, m00 * wx0));
      const float s1 = fmaf(m12, wx2, fmaf(m11, wx1, m10 * wx0));
      const float s2 = fmaf(m22, wx2, fmaf(m21, wx1, m20 * wx0));
      rp[j] = fmaf(wy2, s2, fmaf(wy1, s1, wy0 * s0));
      ix += dix;
      iy += diy;
    }
    *(float4*)(op + i * 16 * 64) = rv;
  }
}

extern "C" void kernel_launch(void* const* d_in, const int* in_sizes, int n_in,
                              void* d_out, int out_size, void* d_ws, size_t ws_size,
                              hipStream_t stream) {
  const float* z     = (const float*)d_in[0];
  const float* Wm    = (const float*)d_in[1];
  const float* bm    = (const float*)d_in[2];
  const float* Wt    = (const float*)d_in[3];
  const float* bt    = (const float*)d_in[4];
  const float* noise = (const float*)d_in[5];
  float* out = (float*)d_out;

  const size_t need = (size_t)BATCH * NPATCH * 16 * sizeof(float);
  if (d_ws != nullptr && ws_size >= need) {
    float* ws = (float*)d_ws;
    hipLaunchKernelGGL(k_gemm, dim3(NPATCH, 4), dim3(256), 0, stream,
                       z, Wm, bm, Wt, bt, noise, ws);
    // one wave per image: 8192 images / 4 waves per block
    hipLaunchKernelGGL(k_sample, dim3(BATCH * NPATCH / 4), dim3(256), 0, stream,
                       ws, out);
  } else {
    hipLaunchKernelGGL(k_fused, dim3(BATCH * NPATCH), dim3(256), 0, stream,
                       z, Wm, bm, Wt, bt, noise, out);
  }
}